// Round 5
// baseline (314.937 us; speedup 1.0000x reference)
//
#include <hip/hip_runtime.h>

#define NUM_C 512
#define HW    32768     // 128*256
#define K     19
#define NT    256
#define CP    (NUM_C + 4)       // padded LDS row stride in finalize

// ---------------------------------------------------------------------------
// K1: per-(b,c) plane segment sums via PRIVATE per-thread LDS bins.
// Rounds 0/4 proved the dense compare/select loop is MLP-capped at
// ~2.2 TB/s aggregate (3 loads in flight, 608-cycle VALU body between
// load bursts; duration identical at 1024 and 2048 blocks). Round 2
// proved LDS *atomics* serialize (~200 cyc/wave64). This version:
//   - each thread owns bins[tid*19 .. +19) of float2 (S,T interleaved):
//     per element 1 ds_read_b64 + 2 v_add + 1 ds_write_b64, no atomics,
//     no races (DS ops are in-order per wave -> RMW safe).
//   - load stream unrolled x4: 12 loads in flight per wave (vs 3).
//   - LDS 38.9 KB/block -> 4 blocks/CU; grid = 1024 = one full round.
// Accumulation order per (plane,k) is bit-identical to the round-0 path
// (skipping the +0*s terms of the dense formulation is exact in fp32).
// ---------------------------------------------------------------------------
__global__ __launch_bounds__(NT) void seg_sum_kernel(
    const float* __restrict__ S, const float* __restrict__ T,
    const int* __restrict__ lbl,
    float* __restrict__ pS, float* __restrict__ pT,
    int* __restrict__ pC,
    float* __restrict__ out)
{
    __shared__ float2 bins[NT * K];          // 38,912 B, thread-private slices
    __shared__ float redS[4 * K], redT[4 * K];

    const int tid   = threadIdx.x;
    const int plane = blockIdx.x;            // b*512 + c
    const int b     = plane >> 9;
    const int c     = plane & 511;

    if (plane == 0 && tid == 0) out[0] = 0.f;   // zero-init for K2's atomicAdd

    float2* mybin = &bins[tid * K];
#pragma unroll
    for (int k = 0; k < K; ++k) mybin[k] = make_float2(0.f, 0.f);
    // no barrier needed: each thread touches only its own slice until the tail

    const float4* S4 = (const float4*)(S + (size_t)plane * HW);
    const float4* T4 = (const float4*)(T + (size_t)plane * HW);
    const int4*   L4 = (const int4*)(lbl + (size_t)b * HW);

#define UPD(lv, sv, tv) { float2 v = mybin[lv]; v.x += (sv); v.y += (tv); mybin[lv] = v; }

    for (int i = tid; i < HW / 4; i += 4 * NT) {   // 8 macro-iters, 12 loads each
        float4 s0 = S4[i];          float4 t0 = T4[i];          int4 l0 = L4[i];
        float4 s1 = S4[i + NT];     float4 t1 = T4[i + NT];     int4 l1 = L4[i + NT];
        float4 s2 = S4[i + 2*NT];   float4 t2 = T4[i + 2*NT];   int4 l2 = L4[i + 2*NT];
        float4 s3 = S4[i + 3*NT];   float4 t3 = T4[i + 3*NT];   int4 l3 = L4[i + 3*NT];
        UPD(l0.x, s0.x, t0.x); UPD(l0.y, s0.y, t0.y); UPD(l0.z, s0.z, t0.z); UPD(l0.w, s0.w, t0.w);
        UPD(l1.x, s1.x, t1.x); UPD(l1.y, s1.y, t1.y); UPD(l1.z, s1.z, t1.z); UPD(l1.w, s1.w, t1.w);
        UPD(l2.x, s2.x, t2.x); UPD(l2.y, s2.y, t2.y); UPD(l2.z, s2.z, t2.z); UPD(l2.w, s2.w, t2.w);
        UPD(l3.x, s3.x, t3.x); UPD(l3.y, s3.y, t3.y); UPD(l3.z, s3.z, t3.z); UPD(l3.w, s3.w, t3.w);
    }
#undef UPD

    // cross-thread reduce: wave shuffle (6 steps) -> LDS (4 waves) -> global
    const int lane = tid & 63, wv = tid >> 6;
#pragma unroll
    for (int k = 0; k < K; ++k) {
        float2 v2 = mybin[k];
        float vs = v2.x, vt = v2.y;
#pragma unroll
        for (int off = 32; off > 0; off >>= 1) {
            vs += __shfl_down(vs, off);
            vt += __shfl_down(vt, off);
        }
        if (lane == 0) { redS[wv * K + k] = vs; redT[wv * K + k] = vt; }
    }
    __syncthreads();
    if (tid < K) {
        pS[(size_t)plane * K + tid] = redS[tid] + redS[K + tid] + redS[2 * K + tid] + redS[3 * K + tid];
        pT[(size_t)plane * K + tid] = redT[tid] + redT[K + tid] + redT[2 * K + tid] + redT[3 * K + tid];
    }

    // label counts: only the 2 blocks with c==0 (block-uniform branch)
    if (c == 0) {
        int cnt[K];
#pragma unroll
        for (int k = 0; k < K; ++k) cnt[k] = 0;
        for (int i = tid; i < HW / 4; i += NT) {
            int4 l = L4[i];
#pragma unroll
            for (int k = 0; k < K; ++k)
                cnt[k] += (l.x == k) + (l.y == k) + (l.z == k) + (l.w == k);
        }
        __shared__ int redc[4 * K];
#pragma unroll
        for (int k = 0; k < K; ++k) {
            int v = cnt[k];
#pragma unroll
            for (int off = 32; off > 0; off >>= 1) v += __shfl_down(v, off);
            if (lane == 0) redc[wv * K + k] = v;
        }
        __syncthreads();
        if (tid < K)
            pC[b * K + tid] =
                redc[tid] + redc[K + tid] + redc[2 * K + tid] + redc[3 * K + tid];
    }
}

// ---------------------------------------------------------------------------
// K2: grid = 2 blocks (one per batch) x 256 threads. Counts precomputed by
// K1's c==0 blocks. Pairwise dots exploit symmetry: 190 upper-triangle
// tasks with fused S/T accumulation.
// ---------------------------------------------------------------------------
__global__ __launch_bounds__(NT) void finalize_kernel(
    const float* __restrict__ pS, const float* __restrict__ pT,
    const int* __restrict__ pC, float* __restrict__ out)
{
    __shared__ float centS[K * CP];
    __shared__ float centT[K * CP];
    __shared__ float cntf[K];
    __shared__ float dS[K * K], dT[K * K];
    __shared__ float red[NT];
    const int tid = threadIdx.x;
    const int b   = blockIdx.x;

    if (tid < K) cntf[tid] = (float)pC[b * K + tid] + 1e-6f;
    __syncthreads();

    // centers: [k][c] layout, padded stride
    for (int j = tid; j < NUM_C * K; j += NT) {
        int c = j / K, k = j - (j / K) * K;
        size_t gi = (size_t)(b * NUM_C + c) * K + k;
        float cn = cntf[k];
        centS[k * CP + c] = pS[gi] / cn;
        centT[k * CP + c] = pT[gi] / cn;
    }
    __syncthreads();

    // upper-triangle pairwise dots: q in [0, K*(K+1)/2) = [0,190)
    for (int q = tid; q < K * (K + 1) / 2; q += NT) {
        int i = 0, r = q;
        while (r >= K - i) { r -= K - i; ++i; }
        int j = i + r;
        const float4* Si = (const float4*)(centS + i * CP);
        const float4* Sj = (const float4*)(centS + j * CP);
        const float4* Ti = (const float4*)(centT + i * CP);
        const float4* Tj = (const float4*)(centT + j * CP);
        float ds = 0.f, dt = 0.f;
        for (int c4 = 0; c4 < NUM_C / 4; ++c4) {
            float4 xs = Si[c4], ys = Sj[c4];
            ds = fmaf(xs.x, ys.x, ds); ds = fmaf(xs.y, ys.y, ds);
            ds = fmaf(xs.z, ys.z, ds); ds = fmaf(xs.w, ys.w, ds);
            float4 xt = Ti[c4], yt = Tj[c4];
            dt = fmaf(xt.x, yt.x, dt); dt = fmaf(xt.y, yt.y, dt);
            dt = fmaf(xt.z, yt.z, dt); dt = fmaf(xt.w, yt.w, dt);
        }
        dS[i * K + j] = ds; dS[j * K + i] = ds;
        dT[i * K + j] = dt; dT[j * K + i] = dt;
    }
    __syncthreads();

    // cosine-normalize via diagonal + squared diff
    float acc = 0.f;
    for (int p = tid; p < K * K; p += NT) {
        int i = p / K, j = p - (p / K) * K;
        float nsi = fmaxf(sqrtf(dS[i * K + i]), 1e-8f);
        float nsj = fmaxf(sqrtf(dS[j * K + j]), 1e-8f);
        float nti = fmaxf(sqrtf(dT[i * K + i]), 1e-8f);
        float ntj = fmaxf(sqrtf(dT[j * K + j]), 1e-8f);
        float d = dS[p] / (nsi * nsj) - dT[p] / (nti * ntj);
        acc = fmaf(d, d, acc);
    }
    red[tid] = acc;
    __syncthreads();
    for (int s = NT / 2; s > 0; s >>= 1) {
        if (tid < s) red[tid] += red[tid + s];
        __syncthreads();
    }
    if (tid == 0)
        atomicAdd(out, red[0] * (1.0f / (2.0f * K * K)));  // mean over [B,K,K]
}

extern "C" void kernel_launch(void* const* d_in, const int* in_sizes, int n_in,
                              void* d_out, int out_size, void* d_ws, size_t ws_size,
                              hipStream_t stream) {
    const float* S   = (const float*)d_in[0];   // preds_S  [2,512,128,256] fp32
    const float* T   = (const float*)d_in[1];   // preds_T  [2,512,128,256] fp32
    const int*   lbl = (const int*)d_in[2];     // target   [2,1,128,256] int32
    float* out = (float*)d_out;

    // workspace: pS[1024*19] f32, pT[1024*19] f32, pC[2*19] i32  (~156 KB)
    float* pS = (float*)d_ws;
    float* pT = pS + (size_t)2 * NUM_C * K;
    int*   pC = (int*)(pT + (size_t)2 * NUM_C * K);

    seg_sum_kernel<<<2 * NUM_C, NT, 0, stream>>>(S, T, lbl, pS, pT, pC, out);
    finalize_kernel<<<2, NT, 0, stream>>>(pS, pT, pC, out);
}